// Round 4
// baseline (114.028 us; speedup 1.0000x reference)
//
#include <hip/hip_runtime.h>
#include <hip/hip_bf16.h>
#include <stdint.h>

typedef __attribute__((ext_vector_type(8))) short bf16x8;
typedef __attribute__((ext_vector_type(4))) float f32x4;

#define NB 8192

__device__ __forceinline__ unsigned pkbf(float x, float y) {
    __hip_bfloat162 h = __float22bfloat162_rn(make_float2(x, y));  // v_cvt_pk_bf16_f32 (RNE)
    unsigned r;
    __builtin_memcpy(&r, &h, 4);
    return r;
}

__device__ __forceinline__ uint4 pack8(float4 a, float4 b) {
    uint4 r;
    r.x = pkbf(a.x, a.y);
    r.y = pkbf(a.z, a.w);
    r.z = pkbf(b.x, b.y);
    r.w = pkbf(b.z, b.w);
    return r;
}

__device__ __forceinline__ void gload_lds16(const float* g, void* l) {
    __builtin_amdgcn_global_load_lds(
        (const __attribute__((address_space(1))) void*)g,
        (__attribute__((address_space(3))) void*)l, 16, 0, 0);
}

// ---------------------------------------------------------------------------
// prep: W[512][2048] fp32 -> bf16, fragment-linear layout for MFMA B-operand.
// Only k < 1024 ever used. Fragment (kb,cb), kb,cb in [0,32):
//   uint4 index = (kb*32 + cb)*64 + lane
//   element j (0..7) = W[cb*16 + (lane&15)][kb*32 + (lane>>4)*8 + j]
// ---------------------------------------------------------------------------
__global__ __launch_bounds__(256)
void prep_w_kernel(const float* __restrict__ W, uint4* __restrict__ Wt) {
    int t = blockIdx.x * 256 + threadIdx.x;   // 0..65535
    int lane = t & 63;
    int frag = t >> 6;                         // kb*32 + cb
    int kb = frag >> 5, cb = frag & 31;
    int o = cb * 16 + (lane & 15);
    int k = kb * 32 + ((lane >> 4) << 3);
    const float* src = W + (size_t)o * 2048 + k;
    float4 a = *(const float4*)src;
    float4 b = *(const float4*)(src + 4);
    Wt[t] = pack8(a, b);
}

// ---------------------------------------------------------------------------
// score kernel v3: grid 768 = 6 nodes (bid%6, interleaved) x 128 row-tiles.
// BM=64, BN=512, BK=64. 512 threads = 8 waves, wave w owns cols [w*64,+64).
// A staged fp32 via global_load_lds (async DMA, no reg roundtrip), fp32->bf16
// conversion on the ds_read side. LDS tile [64 rows][64 k fp32] = 16 KB,
// double-buffered; 16B slots XOR-swizzled by (row&7): swizzle applied to the
// per-lane GLOBAL source address (gload_lds dest must be linear) and to the
// fragment ds_read address. One __syncthreads per stage: its vmcnt(0) drain
// guarantees the next tile's DMA has landed (m97 structure).
// ---------------------------------------------------------------------------
__global__ __launch_bounds__(512, 4)
void score_kernel(const float* __restrict__ x0, const float* __restrict__ x1,
                  const float* __restrict__ x2, const float* __restrict__ x3,
                  const float* __restrict__ x4, const float* __restrict__ x5,
                  const float* __restrict__ bias, const float* __restrict__ hvec,
                  const uint4* __restrict__ Wt, float* __restrict__ scores) {
    __shared__ uint4 lA[2][1024];     // 2 x 16 KB fp32 tiles
    __shared__ float red[8][64];

    int bid = blockIdx.x;
    int node = bid % 6;
    int tile = bid / 6;               // 0..127
    const float* xp; int dn;
    switch (node) {
        case 0: xp = x0; dn = 1024; break;
        case 1: xp = x1; dn = 512;  break;
        case 2: xp = x2; dn = 512;  break;
        case 3: xp = x3; dn = 512;  break;
        case 4: xp = x4; dn = 1024; break;
        default: xp = x5; dn = 512; break;
    }
    int m0 = tile * 64;
    int t = threadIdx.x;
    int lane = t & 63;
    int w = t >> 6;

    int nst = dn >> 6;                // BK=64 stages: 16 or 8

    // --- staging geometry: wave w issues 2 gload_lds, instr i covers LDS
    // chunk range [(w*2+i)*64, +64) (16B chunks). chunk c -> row r = c>>4,
    // slot s = c&15; source = unswizzled slot s ^ (r&7).
    int ra = ((w << 1) + 0) * 4 + (lane >> 4);
    int rb = ((w << 1) + 1) * 4 + (lane >> 4);
    int sa = (lane & 15) ^ (ra & 7);
    int sb = (lane & 15) ^ (rb & 7);
    const float* ga = xp + (size_t)(m0 + ra) * dn + (sa << 2);
    const float* gb = xp + (size_t)(m0 + rb) * dn + (sb << 2);
    char* lbaseA = (char*)&lA[0][0] + (((w << 1) + 0) << 10);
    char* lbaseB = (char*)&lA[0][0] + (((w << 1) + 1) << 10);

    // prologue: stage tile 0 into buffer 0
    gload_lds16(ga, lbaseA);
    gload_lds16(gb, lbaseB);
    ga += 64; gb += 64;
    __syncthreads();                  // vmcnt(0) drain -> tile 0 in LDS

    f32x4 acc[4][4];
#pragma unroll
    for (int mf = 0; mf < 4; ++mf)
#pragma unroll
        for (int nf = 0; nf < 4; ++nf)
            acc[mf][nf] = (f32x4){0.f, 0.f, 0.f, 0.f};

    const char* ldsroot = (const char*)&lA[0][0];

    for (int s = 0; s < nst; ++s) {
        int cur = s & 1;
        // issue next tile's DMA into the other buffer (in flight across MFMA)
        if (s + 1 < nst) {
            gload_lds16(ga, lbaseA + ((cur ^ 1) << 14));
            gload_lds16(gb, lbaseB + ((cur ^ 1) << 14));
            ga += 64; gb += 64;
        }
#pragma unroll
        for (int ks = 0; ks < 2; ++ks) {
            int kblock = (s << 1) + ks;
            // B fragments direct from global (L2-hot, fragment-linear)
            const uint4* wp = Wt + (((kblock << 5) + (w << 2)) << 6) + lane;
            bf16x8 bfr[4];
#pragma unroll
            for (int nf = 0; nf < 4; ++nf) {
                uint4 u = wp[nf << 6];
                __builtin_memcpy(&bfr[nf], &u, 16);
            }
            // A fragments: swizzled fp32 ds_read + cvt_pk -> bf16
#pragma unroll
            for (int mf = 0; mf < 4; ++mf) {
                int r = (mf << 4) + (lane & 15);
                int slot = (ks << 3) + ((lane >> 4) << 1);
                int sw = r & 7;
                const char* p = ldsroot + (cur << 14) + (r << 8);
                float4 lo = *(const float4*)(p + (((slot) ^ sw) << 4));
                float4 hi = *(const float4*)(p + (((slot + 1) ^ sw) << 4));
                uint4 pk = pack8(lo, hi);
                bf16x8 afr;
                __builtin_memcpy(&afr, &pk, 16);
#pragma unroll
                for (int nf = 0; nf < 4; ++nf)
                    acc[mf][nf] = __builtin_amdgcn_mfma_f32_16x16x32_bf16(
                        afr, bfr[nf], acc[mf][nf], 0, 0, 0);
            }
        }
        __syncthreads();              // also drains next tile's DMA
    }

    // epilogue: tanh, dot with h, reduce to per-row score
    float bv[4], hv[4];
#pragma unroll
    for (int nf = 0; nf < 4; ++nf) {
        int o = (w << 6) + (nf << 4) + (lane & 15);
        bv[nf] = bias[o];
        hv[nf] = hvec[o];
    }
#pragma unroll
    for (int mf = 0; mf < 4; ++mf) {
        float sc[4] = {0.f, 0.f, 0.f, 0.f};
#pragma unroll
        for (int nf = 0; nf < 4; ++nf) {
#pragma unroll
            for (int r = 0; r < 4; ++r) {
                float xv = acc[mf][nf][r] + bv[nf];
                float th = 1.f - 2.f * __builtin_amdgcn_rcpf(1.f + __expf(2.f * xv));
                sc[r] = fmaf(hv[nf], th, sc[r]);
            }
        }
#pragma unroll
        for (int r = 0; r < 4; ++r) {
            float v = sc[r];
            v += __shfl_xor(v, 1);
            v += __shfl_xor(v, 2);
            v += __shfl_xor(v, 4);
            v += __shfl_xor(v, 8);
            if ((lane & 15) == 0)
                red[w][(mf << 4) + ((lane >> 4) << 2) + r] = v;
        }
    }
    __syncthreads();
    if (t < 64) {
        float ssum = 0.f;
#pragma unroll
        for (int w2 = 0; w2 < 8; ++w2) ssum += red[w2][t];
        scores[node * NB + m0 + t] = ssum;
    }
}

// ---------------------------------------------------------------------------
// z kernel: one wave per batch. softmax over 6 scores, then
// z[0:512]=sum beta_n x_n ; z[512:1024]=b0*ls+b4*ds ; z[1024:2048]=0
// ---------------------------------------------------------------------------
__global__ __launch_bounds__(256)
void z_kernel(const float* __restrict__ x0, const float* __restrict__ x1,
              const float* __restrict__ x2, const float* __restrict__ x3,
              const float* __restrict__ x4, const float* __restrict__ x5,
              const float* __restrict__ scores, float* __restrict__ out) {
    int wv = threadIdx.x >> 6;
    int lane = threadIdx.x & 63;
    int b = (blockIdx.x << 2) + wv;

    float s0 = scores[b];
    float s1 = scores[NB + b];
    float s2 = scores[2 * NB + b];
    float s3 = scores[3 * NB + b];
    float s4 = scores[4 * NB + b];
    float s5 = scores[5 * NB + b];
    float m = fmaxf(fmaxf(fmaxf(s0, s1), fmaxf(s2, s3)), fmaxf(s4, s5));
    float e0 = __expf(s0 - m), e1 = __expf(s1 - m), e2 = __expf(s2 - m);
    float e3 = __expf(s3 - m), e4 = __expf(s4 - m), e5 = __expf(s5 - m);
    float inv = __builtin_amdgcn_rcpf(e0 + e1 + e2 + e3 + e4 + e5);
    float b0 = e0 * inv, b1 = e1 * inv, b2 = e2 * inv;
    float b3 = e3 * inv, b4 = e4 * inv, b5 = e5 * inv;

    const float* pls = x0 + (size_t)b * 1024;
    const float* pA  = x1 + (size_t)b * 512;
    const float* plm = x2 + (size_t)b * 512;
    const float* pAT = x3 + (size_t)b * 512;
    const float* pds = x4 + (size_t)b * 1024;
    const float* pdm = x5 + (size_t)b * 512;
    float* po = out + (size_t)b * 2048;

#pragma unroll
    for (int j = 0; j < 2; ++j) {
        int c = (j << 8) + (lane << 2);
        float4 vls = *(const float4*)(pls + c);
        float4 vA  = *(const float4*)(pA + c);
        float4 vlm = *(const float4*)(plm + c);
        float4 vAT = *(const float4*)(pAT + c);
        float4 vds = *(const float4*)(pds + c);
        float4 vdm = *(const float4*)(pdm + c);
        float4 r;
        r.x = b0*vls.x + b1*vA.x + b2*vlm.x + b3*vAT.x + b4*vds.x + b5*vdm.x;
        r.y = b0*vls.y + b1*vA.y + b2*vlm.y + b3*vAT.y + b4*vds.y + b5*vdm.y;
        r.z = b0*vls.z + b1*vA.z + b2*vlm.z + b3*vAT.z + b4*vds.z + b5*vdm.z;
        r.w = b0*vls.w + b1*vA.w + b2*vlm.w + b3*vAT.w + b4*vds.w + b5*vdm.w;
        *(float4*)(po + c) = r;
    }
#pragma unroll
    for (int j = 0; j < 2; ++j) {
        int c = 512 + (j << 8) + (lane << 2);
        float4 vls = *(const float4*)(pls + c);
        float4 vds = *(const float4*)(pds + c);
        float4 r;
        r.x = b0*vls.x + b4*vds.x;
        r.y = b0*vls.y + b4*vds.y;
        r.z = b0*vls.z + b4*vds.z;
        r.w = b0*vls.w + b4*vds.w;
        *(float4*)(po + c) = r;
    }
    float4 zz = make_float4(0.f, 0.f, 0.f, 0.f);
#pragma unroll
    for (int j = 0; j < 4; ++j) {
        int c = 1024 + (j << 8) + (lane << 2);
        *(float4*)(po + c) = zz;
    }
}

extern "C" void kernel_launch(void* const* d_in, const int* in_sizes, int n_in,
                              void* d_out, int out_size, void* d_ws, size_t ws_size,
                              hipStream_t stream) {
    const float* x0   = (const float*)d_in[0];  // ls  [8192,1024]
    const float* x1   = (const float*)d_in[1];  // A   [8192,512]
    const float* x2   = (const float*)d_in[2];  // lm  [8192,512]
    const float* x3   = (const float*)d_in[3];  // AT  [8192,512]
    const float* x4   = (const float*)d_in[4];  // ds  [8192,1024]
    const float* x5   = (const float*)d_in[5];  // dm  [8192,512]
    const float* W    = (const float*)d_in[6];  // [512,2048]
    const float* bias = (const float*)d_in[7];  // [512]
    const float* hvec = (const float*)d_in[8];  // [512,1]

    uint4* Wt = (uint4*)d_ws;                              // 1 MB
    float* scores = (float*)((char*)d_ws + (1u << 20));    // 6*8192*4 = 192 KB

    prep_w_kernel<<<256, 256, 0, stream>>>(W, Wt);
    score_kernel<<<768, 512, 0, stream>>>(x0, x1, x2, x3, x4, x5, bias, hvec, Wt, scores);
    z_kernel<<<2048, 256, 0, stream>>>(x0, x1, x2, x3, x4, x5, scores, (float*)d_out);
}

// Round 5
// 101.526 us; speedup vs baseline: 1.1231x; 1.1231x over previous
//
#include <hip/hip_runtime.h>
#include <hip/hip_bf16.h>
#include <stdint.h>

typedef __attribute__((ext_vector_type(8))) short bf16x8;
typedef __attribute__((ext_vector_type(4))) float f32x4;

#define NB 8192

__device__ __forceinline__ unsigned pkbf(float x, float y) {
    __hip_bfloat162 h = __float22bfloat162_rn(make_float2(x, y));  // v_cvt_pk_bf16_f32 (RNE)
    unsigned r;
    __builtin_memcpy(&r, &h, 4);
    return r;
}

__device__ __forceinline__ uint4 pack8(float4 a, float4 b) {
    uint4 r;
    r.x = pkbf(a.x, a.y);
    r.y = pkbf(a.z, a.w);
    r.z = pkbf(b.x, b.y);
    r.w = pkbf(b.z, b.w);
    return r;
}

// ---------------------------------------------------------------------------
// prep: W[512][2048] fp32 -> bf16, fragment-linear layout for MFMA B-operand.
// Only k < 1024 ever used. Fragment (kb,cb), kb,cb in [0,32):
//   uint4 index = (kb*32 + cb)*64 + lane
//   element j (0..7) = W[cb*16 + (lane&15)][kb*32 + (lane>>4)*8 + j]
// ---------------------------------------------------------------------------
__global__ __launch_bounds__(256)
void prep_w_kernel(const float* __restrict__ W, uint4* __restrict__ Wt) {
    int t = blockIdx.x * 256 + threadIdx.x;   // 0..65535
    int lane = t & 63;
    int frag = t >> 6;                         // kb*32 + cb
    int kb = frag >> 5, cb = frag & 31;
    int o = cb * 16 + (lane & 15);
    int k = kb * 32 + ((lane >> 4) << 3);
    const float* src = W + (size_t)o * 2048 + k;
    float4 a = *(const float4*)src;
    float4 b = *(const float4*)(src + 4);
    Wt[t] = pack8(a, b);
}

// ---------------------------------------------------------------------------
// score kernel v5: template<MFN, DN>. BM = MFN*16, BN=512, BK=64.
// 512 threads = 8 waves; wave w owns cols [w*64, w*64+64); wave tile BMx64,
// acc = MFN x 4 fragments. launch_bounds(512,2) -> 256-reg budget so the
// compiler can hoist B-loads + A-prefetch (the round-4 failure was VGPR=60
// serializing every load).
// LDS: bf16 fragment-linear A tiles, double buffered. Chunk c (16B, 8 bf16):
//   frag f = c>>6 (f = ks*MFN+mf), lane l = c&63
//   elem j = A[m0 + (f%MFN)*16 + (l&15)][s*64 + (f/MFN)*32 + (l>>4)*8 + j]
// Writes (thread t -> chunk t [,t+512]) and reads (frag base + lane*16B) are
// both lane-linear -> zero bank conflicts, no swizzle needed.
// Conversion fp32->bf16 happens once per element at stage time.
// Launched as 2 equal-work instantiations (256 blocks each = 1 generation):
//   <4,1024> for nodes {0,4}, <8,512> for nodes {1,2,3,5}.
// ---------------------------------------------------------------------------
template<int MFN, int DN, int NN>
__global__ __launch_bounds__(512, 2)
void score_kernel(const float* __restrict__ p0, const float* __restrict__ p1,
                  const float* __restrict__ p2, const float* __restrict__ p3,
                  int n0, int n1, int n2, int n3,
                  const float* __restrict__ bias, const float* __restrict__ hvec,
                  const uint4* __restrict__ Wt, float* __restrict__ scores) {
    constexpr int BM = MFN * 16;
    constexpr int NST = DN / 64;          // BK=64 stages
    constexpr int FRAGS = 2 * MFN;        // frags per stage (2 kblocks x MFN)

    __shared__ uint4 lA[2][FRAGS * 64];   // bf16 fragment-linear, dbuf
    __shared__ float red[8][BM];

    int bid = blockIdx.x;
    int ni = bid % NN;
    int tile = bid / NN;
    const float* xp; int node;
    switch (ni) {
        case 0: xp = p0; node = n0; break;
        case 1: xp = p1; node = n1; break;
        case 2: xp = p2; node = n2; break;
        default: xp = p3; node = n3; break;
    }
    int m0 = tile * BM;
    int t = threadIdx.x;
    int l = t & 63;
    int w = t >> 6;

    // staging source for chunk c=t (and c=t+512 when MFN==8)
    int cf = t >> 6;                       // first chunk's frag id
    int r1 = (cf % MFN) * 16 + (l & 15);
    int k1 = (cf / MFN) * 32 + ((l >> 4) << 3);
    const float* g1 = xp + (size_t)(m0 + r1) * DN + k1;
    const float* g2 = g1 + 32;             // chunk t+512: same row, ks=1 (MFN==8)

    // prologue: stage tile 0
    {
        float4 a0 = *(const float4*)g1;
        float4 a1 = *(const float4*)(g1 + 4);
        lA[0][t] = pack8(a0, a1);
        if constexpr (MFN == 8) {
            float4 b0 = *(const float4*)g2;
            float4 b1 = *(const float4*)(g2 + 4);
            lA[0][t + 512] = pack8(b0, b1);
        }
    }
    __syncthreads();

    f32x4 acc[MFN][4];
#pragma unroll
    for (int mf = 0; mf < MFN; ++mf)
#pragma unroll
        for (int nf = 0; nf < 4; ++nf)
            acc[mf][nf] = (f32x4){0.f, 0.f, 0.f, 0.f};

    for (int s = 0; s < NST; ++s) {
        int cur = s & 1;
        // A prefetch for stage s+1 (issued early; consumed after the MFMAs)
        float4 a0, a1, b0, b1;
        bool hn = (s + 1) < NST;
        if (hn) {
            const float* q = g1 + (s + 1) * 64;
            a0 = *(const float4*)q;
            a1 = *(const float4*)(q + 4);
            if constexpr (MFN == 8) {
                const float* q2 = g2 + (s + 1) * 64;
                b0 = *(const float4*)q2;
                b1 = *(const float4*)(q2 + 4);
            }
        }
        // B fragments for both kblocks of this stage (L2-hot, fragment-linear)
        bf16x8 bfr[2][4];
#pragma unroll
        for (int ks = 0; ks < 2; ++ks) {
            int kb = (s << 1) + ks;
            const uint4* wp = Wt + (((kb << 5) + (w << 2)) << 6) + l;
#pragma unroll
            for (int nf = 0; nf < 4; ++nf) {
                uint4 u = wp[nf << 6];
                __builtin_memcpy(&bfr[ks][nf], &u, 16);
            }
        }
        // A fragments from LDS (lane-linear ds_read_b128) + MFMA
#pragma unroll
        for (int ks = 0; ks < 2; ++ks) {
#pragma unroll
            for (int mf = 0; mf < MFN; ++mf) {
                uint4 u = lA[cur][(ks * MFN + mf) * 64 + l];
                bf16x8 afr;
                __builtin_memcpy(&afr, &u, 16);
#pragma unroll
                for (int nf = 0; nf < 4; ++nf)
                    acc[mf][nf] = __builtin_amdgcn_mfma_f32_16x16x32_bf16(
                        afr, bfr[ks][nf], acc[mf][nf], 0, 0, 0);
            }
        }
        // stage s+1 into the other buffer
        if (hn) {
            lA[cur ^ 1][t] = pack8(a0, a1);
            if constexpr (MFN == 8)
                lA[cur ^ 1][t + 512] = pack8(b0, b1);
        }
        __syncthreads();
    }

    // epilogue: tanh, dot with h, reduce to per-row score
    float bv[4], hv[4];
#pragma unroll
    for (int nf = 0; nf < 4; ++nf) {
        int o = (w << 6) + (nf << 4) + (l & 15);
        bv[nf] = bias[o];
        hv[nf] = hvec[o];
    }
#pragma unroll
    for (int mf = 0; mf < MFN; ++mf) {
        float sc[4] = {0.f, 0.f, 0.f, 0.f};
#pragma unroll
        for (int nf = 0; nf < 4; ++nf) {
#pragma unroll
            for (int r = 0; r < 4; ++r) {
                float xv = acc[mf][nf][r] + bv[nf];
                float th = 1.f - 2.f * __builtin_amdgcn_rcpf(1.f + __expf(2.f * xv));
                sc[r] = fmaf(hv[nf], th, sc[r]);
            }
        }
#pragma unroll
        for (int r = 0; r < 4; ++r) {
            float v = sc[r];
            v += __shfl_xor(v, 1);
            v += __shfl_xor(v, 2);
            v += __shfl_xor(v, 4);
            v += __shfl_xor(v, 8);
            if ((l & 15) == 0)
                red[w][(mf << 4) + ((l >> 4) << 2) + r] = v;
        }
    }
    __syncthreads();
    if (t < BM) {
        float ssum = 0.f;
#pragma unroll
        for (int w2 = 0; w2 < 8; ++w2) ssum += red[w2][t];
        scores[node * NB + m0 + t] = ssum;
    }
}

// ---------------------------------------------------------------------------
// z kernel: one wave per batch. softmax over 6 scores, then
// z[0:512]=sum beta_n x_n ; z[512:1024]=b0*ls+b4*ds ; z[1024:2048]=0
// ---------------------------------------------------------------------------
__global__ __launch_bounds__(256)
void z_kernel(const float* __restrict__ x0, const float* __restrict__ x1,
              const float* __restrict__ x2, const float* __restrict__ x3,
              const float* __restrict__ x4, const float* __restrict__ x5,
              const float* __restrict__ scores, float* __restrict__ out) {
    int wv = threadIdx.x >> 6;
    int lane = threadIdx.x & 63;
    int b = (blockIdx.x << 2) + wv;

    float s0 = scores[b];
    float s1 = scores[NB + b];
    float s2 = scores[2 * NB + b];
    float s3 = scores[3 * NB + b];
    float s4 = scores[4 * NB + b];
    float s5 = scores[5 * NB + b];
    float m = fmaxf(fmaxf(fmaxf(s0, s1), fmaxf(s2, s3)), fmaxf(s4, s5));
    float e0 = __expf(s0 - m), e1 = __expf(s1 - m), e2 = __expf(s2 - m);
    float e3 = __expf(s3 - m), e4 = __expf(s4 - m), e5 = __expf(s5 - m);
    float inv = __builtin_amdgcn_rcpf(e0 + e1 + e2 + e3 + e4 + e5);
    float b0 = e0 * inv, b1 = e1 * inv, b2 = e2 * inv;
    float b3 = e3 * inv, b4 = e4 * inv, b5 = e5 * inv;

    const float* pls = x0 + (size_t)b * 1024;
    const float* pA  = x1 + (size_t)b * 512;
    const float* plm = x2 + (size_t)b * 512;
    const float* pAT = x3 + (size_t)b * 512;
    const float* pds = x4 + (size_t)b * 1024;
    const float* pdm = x5 + (size_t)b * 512;
    float* po = out + (size_t)b * 2048;

#pragma unroll
    for (int j = 0; j < 2; ++j) {
        int c = (j << 8) + (lane << 2);
        float4 vls = *(const float4*)(pls + c);
        float4 vA  = *(const float4*)(pA + c);
        float4 vlm = *(const float4*)(plm + c);
        float4 vAT = *(const float4*)(pAT + c);
        float4 vds = *(const float4*)(pds + c);
        float4 vdm = *(const float4*)(pdm + c);
        float4 r;
        r.x = b0*vls.x + b1*vA.x + b2*vlm.x + b3*vAT.x + b4*vds.x + b5*vdm.x;
        r.y = b0*vls.y + b1*vA.y + b2*vlm.y + b3*vAT.y + b4*vds.y + b5*vdm.y;
        r.z = b0*vls.z + b1*vA.z + b2*vlm.z + b3*vAT.z + b4*vds.z + b5*vdm.z;
        r.w = b0*vls.w + b1*vA.w + b2*vlm.w + b3*vAT.w + b4*vds.w + b5*vdm.w;
        *(float4*)(po + c) = r;
    }
#pragma unroll
    for (int j = 0; j < 2; ++j) {
        int c = 512 + (j << 8) + (lane << 2);
        float4 vls = *(const float4*)(pls + c);
        float4 vds = *(const float4*)(pds + c);
        float4 r;
        r.x = b0*vls.x + b4*vds.x;
        r.y = b0*vls.y + b4*vds.y;
        r.z = b0*vls.z + b4*vds.z;
        r.w = b0*vls.w + b4*vds.w;
        *(float4*)(po + c) = r;
    }
    float4 zz = make_float4(0.f, 0.f, 0.f, 0.f);
#pragma unroll
    for (int j = 0; j < 4; ++j) {
        int c = 1024 + (j << 8) + (lane << 2);
        *(float4*)(po + c) = zz;
    }
}

extern "C" void kernel_launch(void* const* d_in, const int* in_sizes, int n_in,
                              void* d_out, int out_size, void* d_ws, size_t ws_size,
                              hipStream_t stream) {
    const float* x0   = (const float*)d_in[0];  // ls  [8192,1024]
    const float* x1   = (const float*)d_in[1];  // A   [8192,512]
    const float* x2   = (const float*)d_in[2];  // lm  [8192,512]
    const float* x3   = (const float*)d_in[3];  // AT  [8192,512]
    const float* x4   = (const float*)d_in[4];  // ds  [8192,1024]
    const float* x5   = (const float*)d_in[5];  // dm  [8192,512]
    const float* W    = (const float*)d_in[6];  // [512,2048]
    const float* bias = (const float*)d_in[7];  // [512]
    const float* hvec = (const float*)d_in[8];  // [512,1]

    uint4* Wt = (uint4*)d_ws;                              // 1 MB
    float* scores = (float*)((char*)d_ws + (1u << 20));    // 6*8192*4 = 192 KB

    prep_w_kernel<<<256, 256, 0, stream>>>(W, Wt);
    // dn=1024 nodes {0,4}: BM=64, 128 tiles x 2 = 256 blocks (1 generation)
    score_kernel<4, 1024, 2><<<256, 512, 0, stream>>>(
        x0, x4, x0, x4, 0, 4, 0, 4, bias, hvec, Wt, scores);
    // dn=512 nodes {1,2,3,5}: BM=128, 64 tiles x 4 = 256 blocks (1 generation)
    score_kernel<8, 512, 4><<<256, 512, 0, stream>>>(
        x1, x2, x3, x5, 1, 2, 3, 5, bias, hvec, Wt, scores);
    z_kernel<<<2048, 256, 0, stream>>>(x0, x1, x2, x3, x4, x5, scores, (float*)d_out);
}